// Round 4
// baseline (614.461 us; speedup 1.0000x reference)
//
#include <hip/hip_runtime.h>

using f32x4  = __attribute__((ext_vector_type(4))) float;
using short8 = __attribute__((ext_vector_type(8))) short;

__device__ inline short f2bf(float x) {
    union { float f; unsigned u; } v; v.f = x;
    unsigned r = v.u + 0x7fffu + ((v.u >> 16) & 1u);   // RNE
    return (short)(r >> 16);
}

__device__ inline short8 pack8(float4 a, float4 b) {
    short8 r;
    r[0] = f2bf(a.x); r[1] = f2bf(a.y); r[2] = f2bf(a.z); r[3] = f2bf(a.w);
    r[4] = f2bf(b.x); r[5] = f2bf(b.y); r[6] = f2bf(b.z); r[7] = f2bf(b.w);
    return r;
}

__device__ inline void atomic_pk_add_bf16(short* addr, unsigned pk) {
    asm volatile("global_atomic_pk_add_bf16 %0, %1, off"
                 :: "v"(addr), "v"(pk) : "memory");
}

// ---------------------------------------------------------------------------
// Weight prep: f32 -> bf16 transposed. Layer-1 K permuted:
// k 0..127 = h_src,h_dst; 128..143 = ea (orig rows 129..144); 144 = dist2
// (orig row 128); 145..159 = zero pad. Also WnT[64][128] for node MLP.
// ---------------------------------------------------------------------------
__global__ __launch_bounds__(256) void convert_weights(
    const float* __restrict__ We1, const float* __restrict__ We2,
    const float* __restrict__ Wc1, const float* __restrict__ Wn,
    short* __restrict__ W1T, short* __restrict__ W2T,
    short* __restrict__ Wc1T, short* __restrict__ WnT)
{
    const int i = blockIdx.x * 256 + threadIdx.x;
    if (i < 64 * 160) {
        const int n = i / 160, k = i % 160;
        float v = 0.0f;
        if (k < 128)       v = We1[k * 64 + n];
        else if (k < 144)  v = We1[(129 + k - 128) * 64 + n];
        else if (k == 144) v = We1[128 * 64 + n];
        W1T[i] = f2bf(v);
    }
    if (i < 64 * 128) {
        const int n = i / 128, k = i % 128;
        WnT[i] = f2bf(Wn[k * 64 + n]);
    }
    if (i < 64 * 64) {
        const int n = i / 64, k = i % 64;
        W2T[i]  = f2bf(We2[k * 64 + n]);
        Wc1T[i] = f2bf(Wc1[k * 64 + n]);
    }
}

__global__ __launch_bounds__(256) void convert_h(
    const float* __restrict__ h, short* __restrict__ hb, int n8)
{
    const int i = blockIdx.x * 256 + threadIdx.x;
    if (i < n8) {
        const float4* h4 = reinterpret_cast<const float4*>(h);
        reinterpret_cast<short8*>(hb)[i] = pack8(h4[2 * i], h4[2 * i + 1]);
    }
}

// ---------------------------------------------------------------------------
// Edge pipeline, convoy-free: 64 edges/block, 4 INDEPENDENT waves (16 edges
// each), no __syncthreads. GEMM1 A-fragments loaded per-lane straight from
// global (lane (r16,kg) takes the 16B k-slice of its edge's row). LDS only
// for the wave-private M1/M2 ping-pong + sdir/sdst (10 KB total).
// mfma_f32_16x16x32_bf16; D: col=lane&15, row=(lane>>4)*4+reg  [m89].
// ---------------------------------------------------------------------------
__global__ __launch_bounds__(256, 6) void egnn_edge_mfma(
    const short* __restrict__ hb, const float* __restrict__ pos,
    const int* __restrict__ ei, const float* __restrict__ ea,
    const short* __restrict__ W1T, const short* __restrict__ W2T,
    const short* __restrict__ Wc1T,
    const float* __restrict__ be1, const float* __restrict__ be2,
    const float* __restrict__ bc1, const float* __restrict__ bc2,
    const float* __restrict__ Wc2,
    short* __restrict__ aggb, float* __restrict__ dpos, int E)
{
    __shared__ short M[4][16][72];      // 9216 B, wave-private rows
    __shared__ float sdir[4][3][16];    //  768 B
    __shared__ int   sdst[4][16];       //  256 B  (10240 B total)

    const int tid  = threadIdx.x;
    const int lane = tid & 63;
    const int wave = tid >> 6;
    const int r16  = lane & 15;
    const int kg   = lane >> 4;
    const int eb   = blockIdx.x * 64;

    const int e  = eb + wave * 16 + r16;       // this lane's own edge
    const int ec = min(e, E - 1);
    const int src = ei[ec];
    const int dst = ei[E + ec];

    // ---- geometry (kg groups duplicate; kg==0 publishes) ----
    const float dx = pos[3 * dst + 0] - pos[3 * src + 0];
    const float dy = pos[3 * dst + 1] - pos[3 * src + 1];
    const float dz = pos[3 * dst + 2] - pos[3 * src + 2];
    const float d2 = fminf(dx * dx + dy * dy + dz * dz, 1000.0f);
    const float inv = 1.0f / sqrtf(d2 + 1e-8f);
    if (kg == 0) {
        sdir[wave][0][r16] = dx * inv;
        sdir[wave][1][r16] = dy * inv;
        sdir[wave][2][r16] = dz * inv;
        sdst[wave][r16] = dst;
    }

    // ---- GEMM1 A-fragments: per-lane 16B slices, direct from global ----
    const short8* hs = reinterpret_cast<const short8*>(hb + (size_t)src * 64);
    const short8* hd = reinterpret_cast<const short8*>(hb + (size_t)dst * 64);
    const short8 a0 = hs[kg];          // k =   0 + kg*8
    const short8 a1 = hs[4 + kg];      // k =  32 + kg*8
    const short8 a2 = hd[kg];          // k =  64 + kg*8
    const short8 a3 = hd[4 + kg];      // k =  96 + kg*8
    short8 a4 = {0, 0, 0, 0, 0, 0, 0, 0};
    if (kg < 2) {                      // k = 128..143 : edge_attr
        const float4* eap = reinterpret_cast<const float4*>(ea + (size_t)ec * 16 + kg * 8);
        a4 = pack8(eap[0], eap[1]);
    } else if (kg == 2) {              // k = 144 : dist2
        a4[0] = f2bf(d2);
    }

    // ---- GEMM1: [16,160] @ [160,64] per wave ----
    f32x4 acc1[4];
    #pragma unroll
    for (int nt = 0; nt < 4; ++nt) {
        const float b = be1[r16 + nt * 16];
        acc1[nt] = {b, b, b, b};
    }
    #pragma unroll
    for (int nt = 0; nt < 4; ++nt) {
        const short* wr = W1T + (r16 + nt * 16) * 160 + kg * 8;
        acc1[nt] = __builtin_amdgcn_mfma_f32_16x16x32_bf16(
            a0, *reinterpret_cast<const short8*>(wr), acc1[nt], 0, 0, 0);
        acc1[nt] = __builtin_amdgcn_mfma_f32_16x16x32_bf16(
            a1, *reinterpret_cast<const short8*>(wr + 32), acc1[nt], 0, 0, 0);
        acc1[nt] = __builtin_amdgcn_mfma_f32_16x16x32_bf16(
            a2, *reinterpret_cast<const short8*>(wr + 64), acc1[nt], 0, 0, 0);
        acc1[nt] = __builtin_amdgcn_mfma_f32_16x16x32_bf16(
            a3, *reinterpret_cast<const short8*>(wr + 96), acc1[nt], 0, 0, 0);
        acc1[nt] = __builtin_amdgcn_mfma_f32_16x16x32_bf16(
            a4, *reinterpret_cast<const short8*>(wr + 128), acc1[nt], 0, 0, 0);
    }
    // M1 -> LDS (own wave's rows; in-order wave LDS pipe, no barrier needed)
    #pragma unroll
    for (int nt = 0; nt < 4; ++nt)
        #pragma unroll
        for (int rg = 0; rg < 4; ++rg)
            M[wave][kg * 4 + rg][r16 + nt * 16] = f2bf(fmaxf(acc1[nt][rg], 0.0f));

    // ---- GEMM2: keep f32 acc for agg scatter ----
    const short8 a5 = *reinterpret_cast<const short8*>(&M[wave][r16][kg * 8]);
    const short8 a6 = *reinterpret_cast<const short8*>(&M[wave][r16][32 + kg * 8]);
    f32x4 acc2[4];
    #pragma unroll
    for (int nt = 0; nt < 4; ++nt) {
        const float b = be2[r16 + nt * 16];
        acc2[nt] = {b, b, b, b};
    }
    #pragma unroll
    for (int nt = 0; nt < 4; ++nt) {
        const short* wr = W2T + (r16 + nt * 16) * 64 + kg * 8;
        acc2[nt] = __builtin_amdgcn_mfma_f32_16x16x32_bf16(
            a5, *reinterpret_cast<const short8*>(wr), acc2[nt], 0, 0, 0);
        acc2[nt] = __builtin_amdgcn_mfma_f32_16x16x32_bf16(
            a6, *reinterpret_cast<const short8*>(wr + 32), acc2[nt], 0, 0, 0);
    }
    // M2 overlays M1 (reads above already issued; same-wave order guarantees)
    #pragma unroll
    for (int nt = 0; nt < 4; ++nt)
        #pragma unroll
        for (int rg = 0; rg < 4; ++rg) {
            const float v = fmaxf(acc2[nt][rg], 0.0f);
            acc2[nt][rg] = v;
            M[wave][kg * 4 + rg][r16 + nt * 16] = f2bf(v);
        }

    // ---- GEMM3: coord MLP layer 1 ----
    const short8 a7 = *reinterpret_cast<const short8*>(&M[wave][r16][kg * 8]);
    const short8 a8 = *reinterpret_cast<const short8*>(&M[wave][r16][32 + kg * 8]);
    f32x4 acc3[4];
    #pragma unroll
    for (int nt = 0; nt < 4; ++nt) {
        const float b = bc1[r16 + nt * 16];
        acc3[nt] = {b, b, b, b};
    }
    #pragma unroll
    for (int nt = 0; nt < 4; ++nt) {
        const short* wr = Wc1T + (r16 + nt * 16) * 64 + kg * 8;
        acc3[nt] = __builtin_amdgcn_mfma_f32_16x16x32_bf16(
            a7, *reinterpret_cast<const short8*>(wr), acc3[nt], 0, 0, 0);
        acc3[nt] = __builtin_amdgcn_mfma_f32_16x16x32_bf16(
            a8, *reinterpret_cast<const short8*>(wr + 32), acc3[nt], 0, 0, 0);
    }

    // ---- coef = tanh(relu(c) . Wc2 + bc2) * 0.1 (reduce over 16 cols) ----
    float prt[4] = {0.0f, 0.0f, 0.0f, 0.0f};
    #pragma unroll
    for (int nt = 0; nt < 4; ++nt) {
        const float wv = Wc2[r16 + nt * 16];
        #pragma unroll
        for (int rg = 0; rg < 4; ++rg)
            prt[rg] += fmaxf(acc3[nt][rg], 0.0f) * wv;
    }
    #pragma unroll
    for (int off = 1; off < 16; off <<= 1)
        #pragma unroll
        for (int rg = 0; rg < 4; ++rg)
            prt[rg] += __shfl_xor(prt[rg], off);
    const float bc2v = bc2[0];

    // ---- scatter: dpos (f32 atomics, 3 lanes per edge row) ----
    if (r16 < 3) {
        #pragma unroll
        for (int rg = 0; rg < 4; ++rg) {
            const int erl = kg * 4 + rg;
            if (eb + wave * 16 + erl < E) {
                const float coef = tanhf(prt[rg] + bc2v) * 0.1f;
                unsafeAtomicAdd(&dpos[3 * sdst[wave][erl] + r16],
                                sdir[wave][r16][erl] * coef);
            }
        }
    }
    // ---- scatter: agg += m2 via packed-bf16 atomics (2 cols/op) ----
    #pragma unroll
    for (int rg = 0; rg < 4; ++rg) {
        const int erl = kg * 4 + rg;
        if (eb + wave * 16 + erl < E) {
            short* arow = aggb + (size_t)sdst[wave][erl] * 64;
            #pragma unroll
            for (int nt = 0; nt < 4; ++nt) {
                const float v  = acc2[nt][rg];
                const float vp = __shfl_xor(v, 1);
                if ((r16 & 1) == (nt >> 1)) {   // even lanes: nt 0,1; odd: nt 2,3
                    const int col0 = (r16 & ~1) + nt * 16;
                    const unsigned blo = (unsigned short)f2bf((r16 & 1) ? vp : v);
                    const unsigned bhi = (unsigned short)f2bf((r16 & 1) ? v : vp);
                    atomic_pk_add_bf16(arow + col0, blo | (bhi << 16));
                }
            }
        }
    }
}

// ---------------------------------------------------------------------------
// Node MLP + residual + LayerNorm, MFMA version. 64 nodes/block, 4 waves.
// ---------------------------------------------------------------------------
__global__ __launch_bounds__(256) void egnn_node_mfma(
    const float* __restrict__ h, const short* __restrict__ hb,
    const short* __restrict__ aggb, const float* __restrict__ pos,
    const float* __restrict__ dpos, const short* __restrict__ WnT,
    const float* __restrict__ bn, const float* __restrict__ lng,
    const float* __restrict__ lnb,
    float* __restrict__ h_out, float* __restrict__ pos_out, int N)
{
    __shared__ short As[64][136];   // cols 0..64 = h (bf16), 64..128 = agg
    const int tid = threadIdx.x;
    const int n0  = blockIdx.x * 64;

    // pos_out = pos + dpos
    if (tid < 64) {
        const int n = n0 + tid;
        if (n < N) {
            #pragma unroll
            for (int c = 0; c < 3; ++c)
                pos_out[(size_t)3 * n + c] = pos[(size_t)3 * n + c] + dpos[(size_t)3 * n + c];
        }
    }

    {   // stage [h | agg] rows (sequential -> coalesced)
        const int row = tid >> 2, part = tid & 3;
        const int n = n0 + row;
        if (n < N) {
            const short* sp = (part < 2) ? (hb + (size_t)n * 64 + (part & 1) * 32)
                                         : (aggb + (size_t)n * 64 + (part & 1) * 32);
            #pragma unroll
            for (int q = 0; q < 4; ++q)
                *reinterpret_cast<short8*>(&As[row][part * 32 + q * 8]) =
                    *reinterpret_cast<const short8*>(sp + q * 8);
        }
    }
    __syncthreads();

    const int lane = tid & 63;
    const int wave = tid >> 6;
    const int r16  = lane & 15;
    const int kg   = lane >> 4;
    const int mrow = wave * 16 + r16;

    f32x4 acc[4];
    #pragma unroll
    for (int nt = 0; nt < 4; ++nt) {
        const float b = bn[r16 + nt * 16];
        acc[nt] = {b, b, b, b};
    }
    #pragma unroll
    for (int kt = 0; kt < 4; ++kt) {
        short8 a = *reinterpret_cast<const short8*>(&As[mrow][kt * 32 + kg * 8]);
        #pragma unroll
        for (int nt = 0; nt < 4; ++nt) {
            short8 b = *reinterpret_cast<const short8*>(
                &WnT[(r16 + nt * 16) * 128 + kt * 32 + kg * 8]);
            acc[nt] = __builtin_amdgcn_mfma_f32_16x16x32_bf16(a, b, acc[nt], 0, 0, 0);
        }
    }

    // x = h + relu(acc), residual from f32 h
    float xv[4][4];
    #pragma unroll
    for (int rg = 0; rg < 4; ++rg) {
        const int n = n0 + wave * 16 + kg * 4 + rg;
        const bool ok = n < N;
        #pragma unroll
        for (int nt = 0; nt < 4; ++nt)
            xv[nt][rg] = (ok ? h[(size_t)n * 64 + r16 + nt * 16] : 0.0f)
                         + fmaxf(acc[nt][rg], 0.0f);
    }

    float g[4], bb[4];
    #pragma unroll
    for (int nt = 0; nt < 4; ++nt) { g[nt] = lng[r16 + nt * 16]; bb[nt] = lnb[r16 + nt * 16]; }

    #pragma unroll
    for (int rg = 0; rg < 4; ++rg) {
        float s = xv[0][rg] + xv[1][rg] + xv[2][rg] + xv[3][rg];
        #pragma unroll
        for (int off = 1; off < 16; off <<= 1) s += __shfl_xor(s, off);
        const float mu = s * 0.015625f;
        float q = 0.0f;
        #pragma unroll
        for (int nt = 0; nt < 4; ++nt) { const float d = xv[nt][rg] - mu; q += d * d; }
        #pragma unroll
        for (int off = 1; off < 16; off <<= 1) q += __shfl_xor(q, off);
        const float inv = rsqrtf(q * 0.015625f + 1e-5f);
        const int n = n0 + wave * 16 + kg * 4 + rg;
        if (n < N) {
            #pragma unroll
            for (int nt = 0; nt < 4; ++nt)
                h_out[(size_t)n * 64 + r16 + nt * 16] =
                    (xv[nt][rg] - mu) * inv * g[nt] + bb[nt];
        }
    }
}

extern "C" void kernel_launch(void* const* d_in, const int* in_sizes, int n_in,
                              void* d_out, int out_size, void* d_ws, size_t ws_size,
                              hipStream_t stream)
{
    const float* h   = (const float*)d_in[0];
    const float* pos = (const float*)d_in[1];
    const int*   ei  = (const int*)d_in[2];
    const float* ea  = (const float*)d_in[3];
    const float* We1 = (const float*)d_in[4];
    const float* be1 = (const float*)d_in[5];
    const float* We2 = (const float*)d_in[6];
    const float* be2 = (const float*)d_in[7];
    const float* Wc1 = (const float*)d_in[8];
    const float* bc1 = (const float*)d_in[9];
    const float* Wc2 = (const float*)d_in[10];
    const float* bc2 = (const float*)d_in[11];
    const float* Wn  = (const float*)d_in[12];
    const float* bn  = (const float*)d_in[13];
    const float* lng = (const float*)d_in[14];
    const float* lnb = (const float*)d_in[15];

    const int N = in_sizes[0] / 64;
    const int E = in_sizes[2] / 2;

    // workspace layout
    short* aggb = (short*)d_ws;                         // [N,64] bf16
    float* dpos = (float*)(aggb + (size_t)N * 64);      // [N,3]  f32
    short* W1T  = (short*)(dpos + (size_t)N * 3);       // [64,160]
    short* W2T  = W1T + 64 * 160;                       // [64,64]
    short* Wc1T = W2T + 64 * 64;                        // [64,64]
    short* WnT  = Wc1T + 64 * 64;                       // [64,128]
    short* hbuf = WnT + 64 * 128;                       // [N,64] bf16

    hipMemsetAsync(d_ws, 0, (size_t)N * 140, stream);   // aggb + dpos
    convert_weights<<<40, 256, 0, stream>>>(We1, We2, Wc1, Wn, W1T, W2T, Wc1T, WnT);
    convert_h<<<(N * 64 / 8 + 255) / 256, 256, 0, stream>>>(h, hbuf, N * 64 / 8);

    float* h_out   = (float*)d_out;
    float* pos_out = h_out + (size_t)N * 64;

    egnn_edge_mfma<<<(E + 63) / 64, 256, 0, stream>>>(
        hbuf, pos, ei, ea, W1T, W2T, Wc1T, be1, be2, bc1, bc2, Wc2, aggb, dpos, E);
    egnn_node_mfma<<<(N + 63) / 64, 256, 0, stream>>>(
        h, hbuf, aggb, pos, dpos, WnT, bn, lng, lnb, h_out, pos_out, N);
}